// Round 2
// baseline (640.460 us; speedup 1.0000x reference)
//
#include <hip/hip_runtime.h>
#include <hip/hip_cooperative_groups.h>

namespace cg = cooperative_groups;

#define N_ROWS   131072
#define D_IN     256
#define D_MID    128
#define N_SUBS   64

// ---- geometry: 1024 blocks x 256 threads = 4096 waves x 32 rows ----
// Co-residency for cooperative launch: __launch_bounds__(256,4) caps VGPR at
// 128 -> >=4 blocks/CU -> >=1024 blocks resident on 256 CUs. We use ~40 VGPR.
#define NBLK     1024
#define NTHR     256
#define NWAVE    (NBLK * NTHR / 64)      // 4096
#define RPW      (N_ROWS / NWAVE)        // 32 rows per wave

// ws layout: rowsum[N_ROWS] | partials[2*N_SUBS][NBLK] (slot-major) | gfin[2*N_SUBS]

__global__ __launch_bounds__(NTHR, 4) void fused(const float* __restrict__ x,
                                                 const int* __restrict__ sub,
                                                 const float* __restrict__ Gamma,
                                                 const float* __restrict__ Lambda,
                                                 float* __restrict__ out,
                                                 float* __restrict__ rowsum,
                                                 float* __restrict__ partials,
                                                 float* __restrict__ gfin) {
    cg::grid_group grid = cg::this_grid();
    __shared__ float ls[2 * N_SUBS];     // phase A bins; ls[0..3] reused in B
    __shared__ float tg[N_SUBS];         // phase C per-group term
    int tid  = threadIdx.x;
    int lane = tid & 63;
    int gwave = (blockIdx.x * NTHR + tid) >> 6;

    if (tid < 2 * N_SUBS) ls[tid] = 0.0f;
    __syncthreads();

    // ---- Phase A: rowsums + per-block group bins -------------------------
    // Strided row map: at step r the whole grid streams a contiguous 4 MB
    // slab (same pattern as the 6.8 TB/s fill kernel). Wave reads 1 KiB/row.
    #pragma unroll 4
    for (int r = 0; r < RPW; ++r) {
        int row = gwave + r * NWAVE;
        float4 v = ((const float4*)(x + (size_t)row * D_IN))[lane];
        float s = (v.x + v.y) + (v.z + v.w);
        #pragma unroll
        for (int m = 32; m >= 1; m >>= 1) s += __shfl_xor(s, m, 64);
        if (lane == 0) {
            rowsum[row] = s;
            int g = sub[row];
            atomicAdd(&ls[g], s);                 // LDS atomics, 64/row-set per block
            atomicAdd(&ls[N_SUBS + g], 1.0f);
        }
    }
    __syncthreads();
    // slot-major store so phase B reads are coalesced along the block axis
    if (tid < 2 * N_SUBS) partials[(size_t)tid * NBLK + blockIdx.x] = ls[tid];
    __threadfence();
    grid.sync();

    // ---- Phase B: blocks 0..127 reduce one slot each (1024 floats) -------
    if (blockIdx.x < 2 * N_SUBS) {
        const float* src = partials + (size_t)blockIdx.x * NBLK;
        float a = src[tid] + src[tid + 256] + src[tid + 512] + src[tid + 768];
        #pragma unroll
        for (int m = 32; m >= 1; m >>= 1) a += __shfl_xor(a, m, 64);
        if (lane == 0) ls[tid >> 6] = a;          // 4 wave partials
        __syncthreads();
        if (tid == 0) gfin[blockIdx.x] = ls[0] + ls[1] + ls[2] + ls[3];
    }
    __threadfence();
    grid.sync();

    // ---- Phase C: per-group term once, then stream broadcast output ------
    if (tid < N_SUBS) {
        float sum = gfin[tid];
        float cnt = gfin[N_SUBS + tid];
        // empty-group fallback: mean over x[0] -> meansum == rowsum[0]
        float meansum = (cnt > 0.0f) ? (sum / cnt) : rowsum[0];
        float s = Gamma[0] * meansum;
        s = s > 0.0f ? s : 0.0f;                  // relu
        tg[tid] = Lambda[0] * (float)D_MID * s;
    }
    __syncthreads();

    float lam = Lambda[0];
    #pragma unroll 4
    for (int r = 0; r < RPW; ++r) {
        int row = gwave + r * NWAVE;
        float o = lam * rowsum[row] + tg[sub[row]];   // broadcast scalar loads (L2-hot)
        o = o > 0.0f ? o : 0.0f;                      // relu
        ((float4*)(out + (size_t)row * D_IN))[lane] = make_float4(o, o, o, o);
    }
}

extern "C" void kernel_launch(void* const* d_in, const int* in_sizes, int n_in,
                              void* d_out, int out_size, void* d_ws, size_t ws_size,
                              hipStream_t stream) {
    const float* x      = (const float*)d_in[0];
    const int*   sub    = (const int*)d_in[1];
    const float* Gamma  = (const float*)d_in[2];
    const float* Lambda = (const float*)d_in[3];
    float* out = (float*)d_out;

    float* rowsum   = (float*)d_ws;                       // N_ROWS floats
    float* partials = rowsum + N_ROWS;                    // 128 * NBLK floats
    float* gfin     = partials + 2 * N_SUBS * NBLK;       // 128 floats

    void* args[] = {(void*)&x, (void*)&sub, (void*)&Gamma, (void*)&Lambda,
                    (void*)&out, (void*)&rowsum, (void*)&partials, (void*)&gfin};
    hipLaunchCooperativeKernel((void*)fused, dim3(NBLK), dim3(NTHR), args, 0, stream);
}

// Round 3
// 304.648 us; speedup vs baseline: 2.1023x; 2.1023x over previous
//
#include <hip/hip_runtime.h>

#define N_ROWS   131072
#define D_IN     256
#define D_MID    128
#define N_SUBS   64

// Both kernels: 2048 blocks x 256 threads = 8 blocks/CU x 4 waves = 32 waves/CU
// (max occupancy; ~30 VGPR, 512 B LDS). 8192 waves x 16 rows each.
#define NBLK   2048
#define NTHR   256
#define NWAVE  (NBLK * NTHR / 64)        // 8192
#define RPW    (N_ROWS / NWAVE)          // 16

// ws layout: rowsum[N_ROWS] | gbins[128] (64 sums + 64 counts)

// K1: wave-per-row streaming read of x (float4, 1 KiB/wave/row), 6-step
// shfl_xor reduce, lane 0 stores rowsum + LDS-bins by group. Epilogue: 128
// global atomicAdds per block into gbins (262K atomics over 128 addresses,
// L2-side, ~3 us overlapped with the stream).
__global__ __launch_bounds__(256) void k1_rowsum_bins(const float* __restrict__ x,
                                                      const int* __restrict__ sub,
                                                      float* __restrict__ rowsum,
                                                      float* __restrict__ gbins) {
    __shared__ float ls[2 * N_SUBS];
    if (threadIdx.x < 2 * N_SUBS) ls[threadIdx.x] = 0.0f;
    __syncthreads();

    int gwave = (blockIdx.x * NTHR + threadIdx.x) >> 6;
    int lane  = threadIdx.x & 63;

    #pragma unroll 4
    for (int r = 0; r < RPW; ++r) {
        int row = gwave + r * NWAVE;
        float4 v = ((const float4*)(x + (size_t)row * D_IN))[lane];
        float s = (v.x + v.y) + (v.z + v.w);
        #pragma unroll
        for (int m = 32; m >= 1; m >>= 1) s += __shfl_xor(s, m, 64);
        if (lane == 0) {
            rowsum[row] = s;
            int g = sub[row];
            atomicAdd(&ls[g], s);                 // LDS atomic
            atomicAdd(&ls[N_SUBS + g], 1.0f);
        }
    }
    __syncthreads();
    if (threadIdx.x < 2 * N_SUBS)
        atomicAdd(&gbins[threadIdx.x], ls[threadIdx.x]);
}

// K2: per-block prologue computes tg[g] = Lambda*128*relu(Gamma*mean) from the
// finished gbins (128 L2-hot scalar loads), then streams the broadcast output:
// o = relu(lam*rowsum[row] + tg[sub[row]]), 64 float4 stores per row — the
// same linear-slab store pattern as the 6.8 TB/s fill kernel.
__global__ __launch_bounds__(256) void k2_out(const float* __restrict__ rowsum,
                                              const int* __restrict__ sub,
                                              const float* __restrict__ gbins,
                                              const float* __restrict__ Gamma,
                                              const float* __restrict__ Lambda,
                                              float* __restrict__ out) {
    __shared__ float tg[N_SUBS];
    int tid = threadIdx.x;
    if (tid < N_SUBS) {
        float sum = gbins[tid];
        float cnt = gbins[N_SUBS + tid];
        // empty-group fallback: mean over x[0] -> meansum == rowsum[0]
        float meansum = (cnt > 0.0f) ? (sum / cnt) : rowsum[0];
        float s = Gamma[0] * meansum;
        s = s > 0.0f ? s : 0.0f;                  // relu
        tg[tid] = Lambda[0] * (float)D_MID * s;
    }
    __syncthreads();

    float lam   = Lambda[0];
    int   gwave = (blockIdx.x * NTHR + tid) >> 6;
    int   lane  = tid & 63;

    #pragma unroll 4
    for (int r = 0; r < RPW; ++r) {
        int row = gwave + r * NWAVE;
        float o = lam * rowsum[row] + tg[sub[row]];   // wave-uniform L2-hot loads
        o = o > 0.0f ? o : 0.0f;                      // relu
        ((float4*)(out + (size_t)row * D_IN))[lane] = make_float4(o, o, o, o);
    }
}

extern "C" void kernel_launch(void* const* d_in, const int* in_sizes, int n_in,
                              void* d_out, int out_size, void* d_ws, size_t ws_size,
                              hipStream_t stream) {
    const float* x      = (const float*)d_in[0];
    const int*   sub    = (const int*)d_in[1];
    const float* Gamma  = (const float*)d_in[2];
    const float* Lambda = (const float*)d_in[3];
    float* out = (float*)d_out;

    float* rowsum = (float*)d_ws;                 // N_ROWS floats
    float* gbins  = rowsum + N_ROWS;              // 128 floats (sums | counts)

    hipMemsetAsync(gbins, 0, 2 * N_SUBS * sizeof(float), stream);  // graph-capturable
    k1_rowsum_bins<<<NBLK, NTHR, 0, stream>>>(x, sub, rowsum, gbins);
    k2_out<<<NBLK, NTHR, 0, stream>>>(rowsum, sub, gbins, Gamma, Lambda, out);
}

// Round 4
// 265.410 us; speedup vs baseline: 2.4131x; 1.1478x over previous
//
#include <hip/hip_runtime.h>

#define N_ROWS   131072
#define D_IN     256
#define D_MID    128
#define N_SUBS   64

// 2048 blocks x 256 threads; block owns 64 contiguous rows (64 KiB slab).
// 4 waves/block x 2 halves x 8 rows. ~56 VGPR, 9.2 KiB LDS -> 8 blocks/CU
// resident (32 waves/CU), whole grid in one round.
#define NBLK   2048
#define NTHR   256

// ws layout: rowsum[N_ROWS] | gbins[128] (64 sums + 64 counts)

// K1: per half-slab, each wave issues 8 independent float4 row-loads with NO
// side effects between them (full MLP), reduces via wave-private LDS
// transpose + 3 cheap shfl_xor (1,2,4), then does ALL per-row side effects in
// one 8-lane coalesced epilogue. Global bin atomics once per block at the end.
__global__ __launch_bounds__(256) void k1_rowsum_bins(const float* __restrict__ x,
                                                      const int* __restrict__ sub,
                                                      float* __restrict__ rowsum,
                                                      float* __restrict__ gbins) {
    __shared__ float part[4][8][68];   // 68-float row stride: 16B-aligned rows, <=2-way banks
    __shared__ float bins[2 * N_SUBS];
    int tid = threadIdx.x;
    if (tid < 2 * N_SUBS) bins[tid] = 0.0f;
    __syncthreads();

    int w    = tid >> 6;
    int lane = tid & 63;

    #pragma unroll
    for (int it = 0; it < 2; ++it) {
        int rbase = blockIdx.x * 64 + it * 32 + w * 8;       // this wave's 8 rows
        const float4* src = (const float4*)(x + (size_t)rbase * D_IN);

        float4 v[8];
        #pragma unroll
        for (int j = 0; j < 8; ++j) v[j] = src[(size_t)j * 64 + lane];  // 8 KiB in flight

        #pragma unroll
        for (int j = 0; j < 8; ++j)
            part[w][j][lane] = (v[j].x + v[j].y) + (v[j].z + v[j].w);

        // wave-private transpose read: 8 lanes per row, 8 floats each
        int myrow = lane >> 3;
        int seg   = lane & 7;
        const float* pr = &part[w][myrow][seg * 8];
        float4 a = *(const float4*)pr;
        float4 b = *(const float4*)(pr + 4);
        float s = ((a.x + a.y) + (a.z + a.w)) + ((b.x + b.y) + (b.z + b.w));
        s += __shfl_xor(s, 1, 64);
        s += __shfl_xor(s, 2, 64);
        s += __shfl_xor(s, 4, 64);                           // all DPP-class hops

        if (seg == 0) {                                      // 8 lanes: rows rbase..rbase+7
            int row = rbase + myrow;
            rowsum[row] = s;                                 // one 32 B transaction/wave
            int g = sub[row];                                // one 32 B transaction/wave
            atomicAdd(&bins[g], s);
            atomicAdd(&bins[N_SUBS + g], 1.0f);
        }
    }
    __syncthreads();
    if (tid < 2 * N_SUBS) {
        float v2 = bins[tid];
        if (v2 != 0.0f) atomicAdd(&gbins[tid], v2);          // ~skip zero slots
    }
}

// K2: per-block prologue builds tg[g] = Lambda*128*relu(Gamma*mean); then each
// wave: lanes 0..7 compute o for its 8 rows (two 32 B coalesced loads), 8
// independent __shfl broadcasts, 8 independent 1 KiB float4 stores. Pure
// store stream; nothing divergent between stores.
__global__ __launch_bounds__(256) void k2_out(const float* __restrict__ rowsum,
                                              const int* __restrict__ sub,
                                              const float* __restrict__ gbins,
                                              const float* __restrict__ Gamma,
                                              const float* __restrict__ Lambda,
                                              float* __restrict__ out) {
    __shared__ float tg[N_SUBS];
    int tid = threadIdx.x;
    if (tid < N_SUBS) {
        float sum = gbins[tid];
        float cnt = gbins[N_SUBS + tid];
        // empty-group fallback: mean over x[0] -> meansum == rowsum[0]
        float meansum = (cnt > 0.0f) ? (sum / cnt) : rowsum[0];
        float s = Gamma[0] * meansum;
        s = s > 0.0f ? s : 0.0f;                             // relu
        tg[tid] = Lambda[0] * (float)D_MID * s;
    }
    __syncthreads();

    float lam  = Lambda[0];
    int w    = tid >> 6;
    int lane = tid & 63;

    #pragma unroll
    for (int it = 0; it < 2; ++it) {
        int rbase = blockIdx.x * 64 + it * 32 + w * 8;
        float o = 0.0f;
        if (lane < 8) {
            int row = rbase + lane;
            o = lam * rowsum[row] + tg[sub[row]];            // 32 B coalesced loads
            o = o > 0.0f ? o : 0.0f;                         // relu
        }
        float4* dst = (float4*)(out + (size_t)rbase * D_IN);
        #pragma unroll
        for (int j = 0; j < 8; ++j) {
            float oj = __shfl(o, j, 64);
            dst[(size_t)j * 64 + lane] = make_float4(oj, oj, oj, oj);
        }
    }
}

extern "C" void kernel_launch(void* const* d_in, const int* in_sizes, int n_in,
                              void* d_out, int out_size, void* d_ws, size_t ws_size,
                              hipStream_t stream) {
    const float* x      = (const float*)d_in[0];
    const int*   sub    = (const int*)d_in[1];
    const float* Gamma  = (const float*)d_in[2];
    const float* Lambda = (const float*)d_in[3];
    float* out = (float*)d_out;

    float* rowsum = (float*)d_ws;                 // N_ROWS floats
    float* gbins  = rowsum + N_ROWS;              // 128 floats (sums | counts)

    hipMemsetAsync(gbins, 0, 2 * N_SUBS * sizeof(float), stream);  // graph-capturable
    k1_rowsum_bins<<<NBLK, NTHR, 0, stream>>>(x, sub, rowsum, gbins);
    k2_out<<<NBLK, NTHR, 0, stream>>>(rowsum, sub, gbins, Gamma, Lambda, out);
}